// Round 3
// baseline (233.170 us; speedup 1.0000x reference)
//
#include <hip/hip_runtime.h>
#include <math.h>

// Problem shape (fixed by the reference): x = (B=4, S=8192, D=1024) float32.
// out[b,s,d] = x[b,s,d] + pos[s,d]
//   pos[s,d] = sin(s / 10000^((d+1)/D)) if d even, cos(...) if d odd.
#define PE_S 8192
#define PE_D 1024
#define PE_B 4

#define PE_BLOCKS 2048
#define PE_THREADS 256
// quads in half the tensor (= batch planes 0..1); pairing q with q+HALFQ gives
// the SAME (s, d) -> one pos quad serves two load/store pairs.
#define PE_HALFQ (PE_B * PE_S * PE_D / 4 / 2)          // 4,194,304
#define PE_STRIDE (PE_BLOCKS * PE_THREADS)             // 524,288 quads/iter
#define PE_ITERS (PE_HALFQ / PE_STRIDE)                // 8

typedef float f32x4 __attribute__((ext_vector_type(4)));

// Native-trig positional value. v_sin_f32/v_cos_f32 take REVOLUTIONS
// (D = sin(S0*2pi)); wrev = 10000^-((j+1)/D) / (2pi) from one v_exp_f32 by
// folding -log2(2pi) into the exponent. fmaf residual makes the s*wrev
// product effectively fp64 for the reduction; error stays within the
// existing ~0.03 arg-sensitivity envelope (absmax 0.03125, unchanged).
__device__ __forceinline__ float pe_sin(float fs, float wrev) {
    float t = fs * wrev;
    float r = t - floorf(t);
    r += fmaf(fs, wrev, -t);            // exact product residual
    return __builtin_amdgcn_sinf(r);    // sin(2*pi*r)
}
__device__ __forceinline__ float pe_cos(float fs, float wrev) {
    float t = fs * wrev;
    float r = t - floorf(t);
    r += fmaf(fs, wrev, -t);
    return __builtin_amdgcn_cosf(r);    // cos(2*pi*r)
}

// RESIDENT-WAVE grid-stride structure (Guideline 11 / m13 copy pattern).
// Previous one-shot version (32768 blocks, 1 quad/thread) reached only
// ~2.8 TB/s: each 131k short-lived wave serialized kernarg-wait -> 1 load ->
// vmcnt(0) -> store -> endpgm, so BW was bound by wave turnover, not HBM.
// Now 2048 blocks stay resident for 8 iterations:
//  - iteration stride (524288 quads) is a multiple of 256 quads -> each
//    thread's d0 is CONSTANT -> the 4 exp2 weights computed once per thread;
//  - quad q (batch planes 0-1) pairs with q+PE_HALFQ (planes 2-3): same
//    (s,d) -> one trig set per TWO load/store pairs, 2 loads in flight.
__global__ __launch_bounds__(PE_THREADS) void position_encoder_kernel(
    const float* __restrict__ x, float* __restrict__ out) {
    const int tid0 = blockIdx.x * blockDim.x + threadIdx.x;  // 0..524287
    const int d0   = (tid0 & (PE_D / 4 - 1)) << 2;           // constant per thread

    const float A2 = -0.012976281620653760f;  // -log2(10000)/1024
    const float C  = -2.6514961294723187f;    // -log2(2*pi)
    // wrev_k = 2^((d0+k)*A2 + C) = 10000^-((d0+k)/1024) / (2*pi) -- once.
    const float w0 = exp2f(fmaf((float)(d0 + 1), A2, C));
    const float w1 = exp2f(fmaf((float)(d0 + 2), A2, C));
    const float w2 = exp2f(fmaf((float)(d0 + 3), A2, C));
    const float w3 = exp2f(fmaf((float)(d0 + 4), A2, C));

#pragma unroll
    for (int it = 0; it < PE_ITERS; ++it) {
        const int q   = tid0 + it * PE_STRIDE;     // quad index in [0, HALFQ)
        const int row = q >> 8;                    // 0..16383 (b*8192+s, b in {0,1})
        const int s   = row & (PE_S - 1);

        const size_t offA = (size_t)q * 4;                       // planes 0-1
        const size_t offB = (size_t)(q + PE_HALFQ) * 4;          // planes 2-3

        // loads first: 2 independent streams in flight while trig runs
        const f32x4 va = *reinterpret_cast<const f32x4*>(x + offA);
        const f32x4 vb = *reinterpret_cast<const f32x4*>(x + offB);

        const float fs = (float)s;
        f32x4 p;
        p.x = pe_sin(fs, w0);   // d0   even -> sin
        p.y = pe_cos(fs, w1);   // d0+1 odd  -> cos
        p.z = pe_sin(fs, w2);   // d0+2 even -> sin
        p.w = pe_cos(fs, w3);   // d0+3 odd  -> cos

        *reinterpret_cast<f32x4*>(out + offA) = va + p;
        *reinterpret_cast<f32x4*>(out + offB) = vb + p;
    }
}

extern "C" void kernel_launch(void* const* d_in, const int* in_sizes, int n_in,
                              void* d_out, int out_size, void* d_ws, size_t ws_size,
                              hipStream_t stream) {
    const float* x = (const float*)d_in[0];
    float* out = (float*)d_out;
    position_encoder_kernel<<<PE_BLOCKS, PE_THREADS, 0, stream>>>(x, out);
}

// Round 4
// 224.893 us; speedup vs baseline: 1.0368x; 1.0368x over previous
//
#include <hip/hip_runtime.h>
#include <math.h>

// Problem shape (fixed by the reference): x = (B=4, S=8192, D=1024) float32.
// out[b,s,d] = x[b,s,d] + pos[s,d]
//   pos[s,d] = sin(s / 10000^((d+1)/D)) if d even, cos(...) if d odd.
#define PE_S 8192
#define PE_D 1024
#define PE_B 4

typedef float f32x4 __attribute__((ext_vector_type(4)));

// Native-trig positional value. v_sin_f32/v_cos_f32 take REVOLUTIONS
// (sin(S0*2pi)); wrev = 10000^-((j+1)/D) / (2pi) from one v_exp_f32 by
// folding -log2(2pi) into the exponent. The fmaf residual makes s*wrev
// effectively fp64 for the fract reduction; error stays within the existing
// ~0.03 arg-sensitivity envelope (absmax 0.03125, unchanged across rounds).
// CRITICAL: branch-free, single basic block -> unlike the ocml sinf/cosf
// calls (rounds 0/1), these do NOT create BB boundaries, so the scheduler
// is free to hoist all 4 plane loads above the whole trig chain.
__device__ __forceinline__ float pe_sin(float fs, float wrev) {
    float t = fs * wrev;
    float r = t - floorf(t);
    r += fmaf(fs, wrev, -t);            // exact product residual
    return __builtin_amdgcn_sinf(r);    // sin(2*pi*r)
}
__device__ __forceinline__ float pe_cos(float fs, float wrev) {
    float t = fs * wrev;
    float r = t - floorf(t);
    r += fmaf(fs, wrev, -t);
    return __builtin_amdgcn_cosf(r);    // cos(2*pi*r)
}

// ROUND-0 STRUCTURE + ROUND-2 TRIG (single change vs the best-known round-2
// baseline): one thread per (s, d-quad), 4 batch-plane load/store pairs.
//  - 4 independent loads (4 KiB/wave) in flight while the short trig chain
//    runs: 4x the per-wave MLP of round 2 (which had 1 KiB/wave and was
//    limited by wave turnover at ~3.7 TB/s, vs fill's 6.7 TB/s same-run).
//  - trig computed ONCE per (s,d) and reused for all 4 planes.
//  - one-shot grid (no grid-stride loop): avoids the loop-carried
//    store-ack -> load vmcnt serialization that regressed round 3.
//  - nt hints on loads AND stores: every byte is touched exactly once per
//    dispatch (no reuse exists), so L2/L3 allocation is pure overhead.
__global__ __launch_bounds__(256) void position_encoder_kernel(
    const float* __restrict__ x, float* __restrict__ out) {
    const int tid = blockIdx.x * blockDim.x + threadIdx.x;  // 0 .. S*D/4-1
    const int d0  = (tid & (PE_D / 4 - 1)) << 2;            // aligned quad start
    const int s   = tid >> 8;                               // 0..8191

    const size_t base  = (size_t)tid * 4;
    const size_t plane = (size_t)PE_S * PE_D;

    // ---- 4 independent plane loads, issued before/under the trig chain ----
    const f32x4 v0 = __builtin_nontemporal_load(
        reinterpret_cast<const f32x4*>(x + 0 * plane + base));
    const f32x4 v1 = __builtin_nontemporal_load(
        reinterpret_cast<const f32x4*>(x + 1 * plane + base));
    const f32x4 v2 = __builtin_nontemporal_load(
        reinterpret_cast<const f32x4*>(x + 2 * plane + base));
    const f32x4 v3 = __builtin_nontemporal_load(
        reinterpret_cast<const f32x4*>(x + 3 * plane + base));

    // ---- trig (branch-free, overlaps the memory latency) ----
    const float A2 = -0.012976281620653760f;  // -log2(10000)/1024
    const float C  = -2.6514961294723187f;    // -log2(2*pi)
    const float w0 = exp2f(fmaf((float)(d0 + 1), A2, C));
    const float w1 = exp2f(fmaf((float)(d0 + 2), A2, C));
    const float w2 = exp2f(fmaf((float)(d0 + 3), A2, C));
    const float w3 = exp2f(fmaf((float)(d0 + 4), A2, C));

    const float fs = (float)s;
    f32x4 p;
    p.x = pe_sin(fs, w0);   // d0   even -> sin
    p.y = pe_cos(fs, w1);   // d0+1 odd  -> cos
    p.z = pe_sin(fs, w2);   // d0+2 even -> sin
    p.w = pe_cos(fs, w3);   // d0+3 odd  -> cos

    // ---- adds + nt stores ----
    __builtin_nontemporal_store(v0 + p, reinterpret_cast<f32x4*>(out + 0 * plane + base));
    __builtin_nontemporal_store(v1 + p, reinterpret_cast<f32x4*>(out + 1 * plane + base));
    __builtin_nontemporal_store(v2 + p, reinterpret_cast<f32x4*>(out + 2 * plane + base));
    __builtin_nontemporal_store(v3 + p, reinterpret_cast<f32x4*>(out + 3 * plane + base));
}

extern "C" void kernel_launch(void* const* d_in, const int* in_sizes, int n_in,
                              void* d_out, int out_size, void* d_ws, size_t ws_size,
                              hipStream_t stream) {
    const float* x = (const float*)d_in[0];
    float* out = (float*)d_out;

    const int threads = 256;
    const int total_quads = PE_S * PE_D / 4;       // 2,097,152 threads
    const int blocks = total_quads / threads;      // 8192 blocks
    position_encoder_kernel<<<blocks, threads, 0, stream>>>(x, out);
}